// Round 5
// baseline (602.245 us; speedup 1.0000x reference)
//
#include <hip/hip_runtime.h>

#define B_ 2
#define S_ 2048
#define E_ 1024
#define H_ 16
#define DH_ 64
#define HID_ 256
#define M_ (B_*S_)

typedef __attribute__((ext_vector_type(8))) short s16x8;
typedef __attribute__((ext_vector_type(4))) float f32x4;
typedef unsigned int u32;
typedef unsigned short u16;
typedef u32 __attribute__((address_space(1))) gu32;
typedef u32 __attribute__((address_space(3))) lu32;

#define MFMA_B16(a,b,c) __builtin_amdgcn_mfma_f32_16x16x32_bf16((a),(b),(c),0,0,0)

__device__ __forceinline__ f32x4 fzero() { f32x4 z = {0.f, 0.f, 0.f, 0.f}; return z; }

// round-to-nearest-even fp32 -> bf16
__device__ __forceinline__ u16 f2bf(float x) {
    u32 u = __float_as_uint(x);
    u32 r = u + 0x7FFFu + ((u >> 16) & 1u);
    return (u16)(r >> 16);
}
__device__ __forceinline__ float bf2f(u16 b) {
    return __uint_as_float(((u32)b) << 16);
}
// per-lane 16B global -> LDS at (wave-uniform base)+lane*16
__device__ __forceinline__ void gload16(const void* gsrc, void* ldst) {
    __builtin_amdgcn_global_load_lds((const gu32*)gsrc, (lu32*)ldst, 16, 0, 0);
}
__device__ __forceinline__ s16x8 lds_frag(const u16* base, int byt) {
    return *(const s16x8*)((const char*)base + byt);
}

// ------------------------------------------------------------- stub
// Only used when ws_size is too small: graceful validation failure
// instead of an out-of-bounds crash (and a diagnostic for us).
__global__ __launch_bounds__(256)
void zfill(float* __restrict__ out, int n)
{
    const int i = blockIdx.x * 256 + threadIdx.x;
    if (i < n) out[i] = 0.f;
}

// ---------------------------------------------------------------- gate
__global__ __launch_bounds__(256)
void gate_kernel(const float* __restrict__ sync_f,
                 const float* __restrict__ Ws1, const float* __restrict__ bs1,
                 const float* __restrict__ Ws2, const float* __restrict__ bs2,
                 float* __restrict__ sw)
{
    __shared__ float xs[E_];
    __shared__ float hid[HID_];
    const int b = blockIdx.x, t = threadIdx.x;
    for (int i = t; i < E_; i += 256) xs[i] = sync_f[b * E_ + i];
    __syncthreads();
    float acc = bs1[t];
    for (int k = 0; k < E_; ++k) acc = fmaf(xs[k], Ws1[k * HID_ + t], acc);
    hid[t] = fmaxf(acc, 0.f);
    __syncthreads();
    if (t < H_) {
        float a = bs2[t];
        for (int k = 0; k < HID_; ++k) a = fmaf(hid[k], Ws2[k * H_ + t], a);
        sw[b * H_ + t] = 1.f / (1.f + __expf(-a));
    }
}

// ------------------------------------------------------------ split x
// fp32 [M][E] -> hi/lo bf16 [M][E]
__global__ __launch_bounds__(256)
void split_x(const float* __restrict__ X, u16* __restrict__ Xhi, u16* __restrict__ Xlo)
{
    const int i = blockIdx.x * 256 + threadIdx.x;   // one 8-elem group
    if (i >= M_ * E_ / 8) return;
    const float4 a = ((const float4*)X)[2 * i];
    const float4 bq = ((const float4*)X)[2 * i + 1];
    float v[8] = {a.x, a.y, a.z, a.w, bq.x, bq.y, bq.z, bq.w};
    s16x8 h, l;
#pragma unroll
    for (int e = 0; e < 8; ++e) {
        u16 hb = f2bf(v[e]);
        h[e] = (short)hb;
        l[e] = (short)f2bf(v[e] - bf2f(hb));
    }
    ((s16x8*)Xhi)[i] = h;
    ((s16x8*)Xlo)[i] = l;
}

// ---------------------------------------------- split + transpose W
// W [E k][E n] fp32 -> Wt_hi/lo [E n][E k] bf16  (64x64 tiles via LDS)
__global__ __launch_bounds__(256)
void split_tw(const float* __restrict__ W, u16* __restrict__ Thi, u16* __restrict__ Tlo)
{
    __shared__ float t[64][65];
    const int k0 = blockIdx.y * 64;
    const int n0 = blockIdx.x * 64;
    const int tid = threadIdx.x;
    const int rr = tid >> 4;            // 0..15
    const int cc = (tid & 15) * 4;
#pragma unroll
    for (int p = 0; p < 4; ++p) {
        float4 v = *(const float4*)&W[(size_t)(k0 + p * 16 + rr) * E_ + n0 + cc];
        t[p * 16 + rr][cc + 0] = v.x;
        t[p * 16 + rr][cc + 1] = v.y;
        t[p * 16 + rr][cc + 2] = v.z;
        t[p * 16 + rr][cc + 3] = v.w;
    }
    __syncthreads();
    const int on = tid >> 2;            // 0..63 (output row n)
    const int ok = (tid & 3) * 16;      // k chunk
    s16x8 h0, h1, l0, l1;
#pragma unroll
    for (int j = 0; j < 8; ++j) {
        float v = t[ok + j][on];
        u16 hb = f2bf(v);
        h0[j] = (short)hb; l0[j] = (short)f2bf(v - bf2f(hb));
        float v2 = t[ok + 8 + j][on];
        u16 hb2 = f2bf(v2);
        h1[j] = (short)hb2; l1[j] = (short)f2bf(v2 - bf2f(hb2));
    }
    size_t o = (size_t)(n0 + on) * E_ + k0 + ok;
    *(s16x8*)&Thi[o] = h0;  *(s16x8*)&Thi[o + 8] = h1;
    *(s16x8*)&Tlo[o] = l0;  *(s16x8*)&Tlo[o + 8] = l1;
}

// ------------------------------------------------- split-bf16 MFMA GEMM
// Out = A[M x E] @ Wt^T + bias  (A hi/lo row-major, Wt = W^T hi/lo row-major)
// 3-pass split: hi*hi + hi*lo + lo*hi (fp32-quality).
// MODE 0: fp32 Out[M][E].  MODE 1: split bf16 -> [B,H,S,DH].  MODE 2: -> [B,H,DH,S].
// LDS tiles [128 rows][32 k] bf16, 64B rows; 16B-slot swizzle s^((r>>1)&3):
// frag reads (rows=l&15 pattern) land 2 lanes/quad = conflict-free.
template<int MODE>
__global__ __launch_bounds__(256)
void gemm_mfma(const u16* __restrict__ Ahi, const u16* __restrict__ Alo,
               const u16* __restrict__ Bhi, const u16* __restrict__ Blo,
               const float* __restrict__ bias,
               float* __restrict__ OutF, u16* __restrict__ OutHi, u16* __restrict__ OutLo)
{
    __shared__ u16 lA[2][128 * 32];
    __shared__ u16 lB[2][128 * 32];
    const int m0 = blockIdx.y * 128, n0 = blockIdx.x * 128;
    const int tid = threadIdx.x;
    const int w = tid >> 6, l = tid & 63;
    const int l15 = l & 15, l4 = l >> 4;
    const int wm = w >> 1, wn = w & 1;

    f32x4 acc[4][4];
#pragma unroll
    for (int i = 0; i < 4; ++i)
#pragma unroll
        for (int j = 0; j < 4; ++j) acc[i][j] = fzero();

    for (int k0 = 0; k0 < E_; k0 += 32) {
        __syncthreads();
        // stage 4 tiles (Ahi,Alo,Bhi,Blo) x 8KB, pre-swizzled source
#pragma unroll
        for (int jj = 0; jj < 8; ++jj) {
            const int idx = w * 8 + jj, tt = idx >> 3, q = idx & 7;
            const int r = q * 16 + (l >> 2);
            const int s = l & 3;
            const int g = s ^ ((r >> 1) & 3);
            const u16* src;
            if (tt == 0)      src = Ahi + (size_t)(m0 + r) * E_ + k0 + 8 * g;
            else if (tt == 1) src = Alo + (size_t)(m0 + r) * E_ + k0 + 8 * g;
            else if (tt == 2) src = Bhi + (size_t)(n0 + r) * E_ + k0 + 8 * g;
            else              src = Blo + (size_t)(n0 + r) * E_ + k0 + 8 * g;
            u16* base = (tt < 2) ? lA[tt] : lB[tt - 2];
            gload16(src, (char*)base + q * 1024);
        }
        __syncthreads();

        s16x8 af[2][4];
#pragma unroll
        for (int hl = 0; hl < 2; ++hl)
#pragma unroll
            for (int mf = 0; mf < 4; ++mf) {
                const int row = wm * 64 + mf * 16 + l15;
                af[hl][mf] = lds_frag(lA[hl], row * 64 + ((l4 ^ ((row >> 1) & 3)) << 4));
            }
#pragma unroll
        for (int nf = 0; nf < 4; ++nf) {
            const int rowb = wn * 64 + nf * 16 + l15;
            const int byt = rowb * 64 + ((l4 ^ ((rowb >> 1) & 3)) << 4);
            s16x8 b0 = lds_frag(lB[0], byt);
            s16x8 b1 = lds_frag(lB[1], byt);
#pragma unroll
            for (int mf = 0; mf < 4; ++mf) {
                acc[mf][nf] = MFMA_B16(af[0][mf], b0, acc[mf][nf]);
                acc[mf][nf] = MFMA_B16(af[0][mf], b1, acc[mf][nf]);
                acc[mf][nf] = MFMA_B16(af[1][mf], b0, acc[mf][nf]);
            }
        }
    }

    // epilogue: D layout col=l&15, row=(l>>4)*4+reg  [m89-verified]
#pragma unroll
    for (int mf = 0; mf < 4; ++mf)
#pragma unroll
        for (int nf = 0; nf < 4; ++nf) {
            const int n = n0 + wn * 64 + nf * 16 + l15;
            const float bb = bias[n];
#pragma unroll
            for (int rr = 0; rr < 4; ++rr) {
                const int m = m0 + wm * 64 + mf * 16 + l4 * 4 + rr;
                const float v = acc[mf][nf][rr] + bb;
                if (MODE == 0) {
                    OutF[(size_t)m * E_ + n] = v;
                } else {
                    const int bat = m >> 11, s = m & (S_ - 1);
                    const int hh = n >> 6, dh = n & 63;
                    const size_t o = (MODE == 1)
                        ? (((size_t)(bat * H_ + hh) * S_ + s) * DH_ + dh)
                        : (((size_t)(bat * H_ + hh) * DH_ + dh) * S_ + s);
                    const u16 hb = f2bf(v);
                    OutHi[o] = hb;
                    OutLo[o] = f2bf(v - bf2f(hb));
                }
            }
        }
}

// ---------------------------------------------------- attention pass 1
// Per block: 128 q-rows of one (b,h); 4 waves x 32-row strips; j-tiles of 64.
// Max-free softmax (|s*scl| <~ 6).  3-pass split QK and PV.
// lK: [64 j][64 k] bf16, 128B rows, slot^(j&7)   (conflict-free B-frags)
// lV: V^T [64 d][64 j] bf16, same swizzle        (PV B-frags contiguous)
// lP: [128 i][64 j] fp32, 256B rows, slot16^((i>>1)&7) (wave-private strips)
__global__ __launch_bounds__(256)
void attn_pass1(const u16* __restrict__ qhi, const u16* __restrict__ qlo,
                const u16* __restrict__ khi, const u16* __restrict__ klo,
                const u16* __restrict__ vthi, const u16* __restrict__ vtlo,
                const float* __restrict__ sw,
                u16* __restrict__ ctxhi, u16* __restrict__ ctxlo,
                float* __restrict__ invl)
{
    __shared__ u16 lK[2][64 * 64];
    __shared__ u16 lV[2][64 * 64];
    __shared__ float lP[128 * 64];
    const int b = blockIdx.z, h = blockIdx.y, i0 = blockIdx.x * 128;
    const int tid = threadIdx.x;
    const int w = tid >> 6, l = tid & 63;
    const int l15 = l & 15, l4 = l >> 4;
    const size_t bh = (size_t)(b * H_ + h);
    const float scl = sw[b * H_ + h] * 0.125f;

    // Q fragments, resident: [hl][rf][kc]
    s16x8 qf[2][2][2];
#pragma unroll
    for (int hl = 0; hl < 2; ++hl)
#pragma unroll
        for (int rf = 0; rf < 2; ++rf)
#pragma unroll
            for (int kc = 0; kc < 2; ++kc) {
                const int row = i0 + w * 32 + rf * 16 + l15;
                const u16* src = (hl ? qlo : qhi) + (bh * S_ + row) * DH_ + kc * 32 + 8 * l4;
                qf[hl][rf][kc] = *(const s16x8*)src;
            }

    f32x4 cacc[2][4];
    float l_acc[2][4];
#pragma unroll
    for (int rf = 0; rf < 2; ++rf) {
#pragma unroll
        for (int df = 0; df < 4; ++df) cacc[rf][df] = fzero();
#pragma unroll
        for (int rr = 0; rr < 4; ++rr) l_acc[rf][rr] = 0.f;
    }

    for (int j0 = 0; j0 < S_; j0 += 64) {
        __syncthreads();   // prior K/V reads done
#pragma unroll
        for (int jj = 0; jj < 8; ++jj) {
            const int idx = w * 8 + jj, tt = idx >> 3, q = idx & 7;
            const int r = q * 8 + (l >> 3);
            const int s = l & 7;
            const int g = s ^ (r & 7);
            const u16* src;
            if (tt == 0)      src = khi  + (bh * S_ + j0 + r) * DH_ + 8 * g;
            else if (tt == 1) src = klo  + (bh * S_ + j0 + r) * DH_ + 8 * g;
            else if (tt == 2) src = vthi + (bh * DH_ + r) * S_ + j0 + 8 * g;
            else              src = vtlo + (bh * DH_ + r) * S_ + j0 + 8 * g;
            u16* base = (tt < 2) ? lK[tt] : lV[tt - 2];
            gload16(src, (char*)base + q * 1024);
        }
        __syncthreads();   // staged tiles visible (syncthreads drains vmcnt)

        // ---- QK^T (3-pass split) ----
        f32x4 p[2][4];
#pragma unroll
        for (int rf = 0; rf < 2; ++rf)
#pragma unroll
            for (int nf = 0; nf < 4; ++nf) p[rf][nf] = fzero();
#pragma unroll
        for (int kc = 0; kc < 2; ++kc) {
            s16x8 kb[2][4];
#pragma unroll
            for (int hl = 0; hl < 2; ++hl)
#pragma unroll
                for (int nf = 0; nf < 4; ++nf) {
                    const int j = nf * 16 + l15;
                    kb[hl][nf] = lds_frag(lK[hl], j * 128 + (((kc * 4 + l4) ^ (j & 7)) << 4));
                }
#pragma unroll
            for (int rf = 0; rf < 2; ++rf)
#pragma unroll
                for (int nf = 0; nf < 4; ++nf) {
                    p[rf][nf] = MFMA_B16(qf[0][rf][kc], kb[0][nf], p[rf][nf]);
                    p[rf][nf] = MFMA_B16(qf[0][rf][kc], kb[1][nf], p[rf][nf]);
                    p[rf][nf] = MFMA_B16(qf[1][rf][kc], kb[0][nf], p[rf][nf]);
                }
        }
        // ---- exp + l accumulation + P -> LDS (wave-private rows) ----
#pragma unroll
        for (int rf = 0; rf < 2; ++rf)
#pragma unroll
            for (int nf = 0; nf < 4; ++nf) {
                const int jcol = nf * 16 + l15;
#pragma unroll
                for (int rr = 0; rr < 4; ++rr) {
                    const float e = __expf(p[rf][nf][rr] * scl);
                    l_acc[rf][rr] += e;
                    const int irow = w * 32 + rf * 16 + l4 * 4 + rr;
                    const int byt = irow * 256 +
                        ((((jcol >> 2) ^ ((irow >> 1) & 7)) << 4) | ((jcol & 3) << 2));
                    *(float*)((char*)lP + byt) = e;
                }
            }
        // ---- PV (3-pass split) ----
#pragma unroll
        for (int kc = 0; kc < 2; ++kc) {
            s16x8 vb[2][4];
#pragma unroll
            for (int hl = 0; hl < 2; ++hl)
#pragma unroll
                for (int df = 0; df < 4; ++df) {
                    const int d = df * 16 + l15;
                    vb[hl][df] = lds_frag(lV[hl], d * 128 + (((kc * 4 + l4) ^ (d & 7)) << 4));
                }
#pragma unroll
            for (int rf = 0; rf < 2; ++rf) {
                const int irow = w * 32 + rf * 16 + l15;
                const int msk = (irow >> 1) & 7;
                float pv8[8];
#pragma unroll
                for (int hh = 0; hh < 2; ++hh) {
                    const int slot = kc * 8 + 2 * l4 + hh;
                    const f32x4 t4 = *(const f32x4*)((const char*)lP +
                                        irow * 256 + ((slot ^ msk) << 4));
                    pv8[hh * 4 + 0] = t4[0]; pv8[hh * 4 + 1] = t4[1];
                    pv8[hh * 4 + 2] = t4[2]; pv8[hh * 4 + 3] = t4[3];
                }
                s16x8 ph, pl;
#pragma unroll
                for (int e = 0; e < 8; ++e) {
                    const u16 hb = f2bf(pv8[e]);
                    ph[e] = (short)hb;
                    pl[e] = (short)f2bf(pv8[e] - bf2f(hb));
                }
#pragma unroll
                for (int df = 0; df < 4; ++df) {
                    cacc[rf][df] = MFMA_B16(ph, vb[0][df], cacc[rf][df]);
                    cacc[rf][df] = MFMA_B16(ph, vb[1][df], cacc[rf][df]);
                    cacc[rf][df] = MFMA_B16(pl, vb[0][df], cacc[rf][df]);
                }
            }
        }
    }

    // reduce l over the 16 col-lanes (butterfly stays within l15 group)
#pragma unroll
    for (int rf = 0; rf < 2; ++rf)
#pragma unroll
        for (int rr = 0; rr < 4; ++rr) {
#pragma unroll
            for (int off = 1; off < 16; off <<= 1)
                l_acc[rf][rr] += __shfl_xor(l_acc[rf][rr], off);
        }
#pragma unroll
    for (int rf = 0; rf < 2; ++rf)
#pragma unroll
        for (int rr = 0; rr < 4; ++rr) {
            const float inv = 1.f / l_acc[rf][rr];
            const int srow = i0 + w * 32 + rf * 16 + l4 * 4 + rr;
            if (l15 == 0) invl[bh * S_ + srow] = inv;
#pragma unroll
            for (int df = 0; df < 4; ++df) {
                const float v = cacc[rf][df][rr] * inv;
                const size_t o = ((size_t)b * S_ + srow) * E_ + h * DH_ + df * 16 + l15;
                const u16 hb = f2bf(v);
                ctxhi[o] = hb;
                ctxlo[o] = f2bf(v - bf2f(hb));
            }
        }
}

// ---------------------------------------------------- attention mean
// amean[b,i,j] = (1/H) sum_h exp(scl_h * q_i.k_j) * invl[b,h,i]
// 3-pass hi/lo split recompute (consistent with pass-1's invl precision).
// 128x128 tile; h inner loop; 4 x 16KB LDS tiles (Qhi,Qlo,Khi,Klo).
__global__ __launch_bounds__(256)
void attn_mean(const u16* __restrict__ qhi, const u16* __restrict__ qlo,
               const u16* __restrict__ khi, const u16* __restrict__ klo,
               const float* __restrict__ sw, const float* __restrict__ invl,
               float* __restrict__ amean)
{
    __shared__ u16 lQ[2][128 * 64];
    __shared__ u16 lKm[2][128 * 64];
    const int b = blockIdx.z, i0 = blockIdx.y * 128, j0 = blockIdx.x * 128;
    const int tid = threadIdx.x;
    const int w = tid >> 6, l = tid & 63;
    const int l15 = l & 15, l4 = l >> 4;

    f32x4 acc[2][8];
#pragma unroll
    for (int rf = 0; rf < 2; ++rf)
#pragma unroll
        for (int nf = 0; nf < 8; ++nf) acc[rf][nf] = fzero();

    for (int h = 0; h < H_; ++h) {
        const size_t bh = (size_t)(b * H_ + h);
        __syncthreads();   // previous head's reads done
#pragma unroll
        for (int jj = 0; jj < 16; ++jj) {
            const int idx = w * 16 + jj, tt = idx >> 4, q = idx & 15;
            const int r = q * 8 + (l >> 3);
            const int s = l & 7;
            const int g = s ^ (r & 7);
            const u16* bsrc = (tt == 0) ? qhi : (tt == 1) ? qlo : (tt == 2) ? khi : klo;
            const int row0 = (tt < 2) ? i0 : j0;
            const u16* src = bsrc + (bh * S_ + row0 + r) * DH_ + 8 * g;
            u16* base = (tt == 0) ? lQ[0] : (tt == 1) ? lQ[1]
                      : (tt == 2) ? lKm[0] : lKm[1];
            gload16(src, (char*)base + q * 1024);
        }
        __syncthreads();

        const float scl = sw[b * H_ + h] * 0.125f;
        float ivl[2][4];
#pragma unroll
        for (int rf = 0; rf < 2; ++rf)
#pragma unroll
            for (int rr = 0; rr < 4; ++rr)
                ivl[rf][rr] = invl[bh * S_ + i0 + w * 32 + rf * 16 + l4 * 4 + rr];

        f32x4 sc[2][8];
#pragma unroll
        for (int rf = 0; rf < 2; ++rf)
#pragma unroll
            for (int nf = 0; nf < 8; ++nf) sc[rf][nf] = fzero();
#pragma unroll
        for (int kc = 0; kc < 2; ++kc) {
            s16x8 qa[2][2];
#pragma unroll
            for (int hl = 0; hl < 2; ++hl)
#pragma unroll
                for (int rf = 0; rf < 2; ++rf) {
                    const int row = w * 32 + rf * 16 + l15;
                    qa[hl][rf] = lds_frag(lQ[hl],
                        row * 128 + (((kc * 4 + l4) ^ (row & 7)) << 4));
                }
#pragma unroll
            for (int nf = 0; nf < 8; ++nf) {
                const int j = nf * 16 + l15;
                const int byt = j * 128 + (((kc * 4 + l4) ^ (j & 7)) << 4);
                const s16x8 kb0 = lds_frag(lKm[0], byt);
                const s16x8 kb1 = lds_frag(lKm[1], byt);
#pragma unroll
                for (int rf = 0; rf < 2; ++rf) {
                    sc[rf][nf] = MFMA_B16(qa[0][rf], kb0, sc[rf][nf]);
                    sc[rf][nf] = MFMA_B16(qa[0][rf], kb1, sc[rf][nf]);
                    sc[rf][nf] = MFMA_B16(qa[1][rf], kb0, sc[rf][nf]);
                }
            }
        }
#pragma unroll
        for (int rf = 0; rf < 2; ++rf)
#pragma unroll
            for (int nf = 0; nf < 8; ++nf)
#pragma unroll
                for (int rr = 0; rr < 4; ++rr)
                    acc[rf][nf][rr] = fmaf(__expf(sc[rf][nf][rr] * scl), ivl[rf][rr],
                                           acc[rf][nf][rr]);
    }

#pragma unroll
    for (int rf = 0; rf < 2; ++rf)
#pragma unroll
        for (int nf = 0; nf < 8; ++nf)
#pragma unroll
            for (int rr = 0; rr < 4; ++rr) {
                const int row = i0 + w * 32 + rf * 16 + l4 * 4 + rr;
                amean[((size_t)b * S_ + row) * S_ + j0 + nf * 16 + l15] =
                    acc[rf][nf][rr] * (1.0f / H_);
            }
}

// ----------------------------------------------------------------------
// Workspace layout (lifetime-overlapped, ~68.5 MB):
//   xhi/xlo : x split (QKV GEMMs)  -> reused as ch/cl (attn output)
//   wt_hi/lo: ONE transpose pair reused for Wq,Wk,Wv,Wo (stream-serialized)
// If ws_size is insufficient, launch only a zero-fill stub (clean
// validation failure instead of an OOB crash).
extern "C" void kernel_launch(void* const* d_in, const int* in_sizes, int n_in,
                              void* d_out, int out_size, void* d_ws, size_t ws_size,
                              hipStream_t stream) {
    (void)in_sizes; (void)n_in;
    const float* x     = (const float*)d_in[0];
    const float* syncf = (const float*)d_in[1];
    const float* Wq    = (const float*)d_in[2];
    const float* bq    = (const float*)d_in[3];
    const float* Wk    = (const float*)d_in[4];
    const float* bk    = (const float*)d_in[5];
    const float* Wv    = (const float*)d_in[6];
    const float* bv    = (const float*)d_in[7];
    const float* Ws1   = (const float*)d_in[8];
    const float* bs1   = (const float*)d_in[9];
    const float* Ws2   = (const float*)d_in[10];
    const float* bs2   = (const float*)d_in[11];
    const float* Wo    = (const float*)d_in[12];
    const float* bo    = (const float*)d_in[13];

    float* outp  = (float*)d_out;
    float* amean = outp + (size_t)M_ * E_;     // out then attn-mean, flat

    char* p = (char*)d_ws;
    auto alloc = [&](size_t bytes) {
        char* r = p; p += (bytes + 255) & ~(size_t)255; return r;
    };
    const size_t SZ_ME  = (size_t)M_ * E_ * 2;        // bf16 [M][E] / [B,H,S,DH]
    const size_t SZ_W   = (size_t)E_ * E_ * 2;        // bf16 [E][E]
    float* swp  = (float*)alloc(128);
    u16* xhi    = (u16*)alloc(SZ_ME);                 // later: ch
    u16* xlo    = (u16*)alloc(SZ_ME);                 // later: cl
    u16* wt_hi  = (u16*)alloc(SZ_W);                  // shared for all 4 weights
    u16* wt_lo  = (u16*)alloc(SZ_W);
    u16* qh     = (u16*)alloc(SZ_ME);
    u16* ql     = (u16*)alloc(SZ_ME);
    u16* kh     = (u16*)alloc(SZ_ME);
    u16* kl     = (u16*)alloc(SZ_ME);
    u16* vth    = (u16*)alloc(SZ_ME);
    u16* vtl    = (u16*)alloc(SZ_ME);
    float* invl = (float*)alloc((size_t)B_ * H_ * S_ * 4);

    const size_t need = (size_t)(p - (char*)d_ws);
    if (ws_size < need) {
        // graceful failure: zero the output, skip the pipeline
        const int n = out_size;
        zfill<<<dim3((n + 255) / 256), 256, 0, stream>>>(outp, n);
        return;
    }

    // aliases (lifetimes do not overlap)
    u16* ch = xhi;
    u16* cl = xlo;

    gate_kernel<<<dim3(B_), 256, 0, stream>>>(syncf, Ws1, bs1, Ws2, bs2, swp);
    split_x<<<dim3(M_ * E_ / 8 / 256), 256, 0, stream>>>(x, xhi, xlo);

    dim3 gt(16, 16);
    dim3 gg(E_ / 128, M_ / 128);
    split_tw<<<gt, 256, 0, stream>>>(Wq, wt_hi, wt_lo);
    gemm_mfma<1><<<gg, 256, 0, stream>>>(xhi, xlo, wt_hi, wt_lo, bq, nullptr, qh, ql);
    split_tw<<<gt, 256, 0, stream>>>(Wk, wt_hi, wt_lo);
    gemm_mfma<1><<<gg, 256, 0, stream>>>(xhi, xlo, wt_hi, wt_lo, bk, nullptr, kh, kl);
    split_tw<<<gt, 256, 0, stream>>>(Wv, wt_hi, wt_lo);
    gemm_mfma<2><<<gg, 256, 0, stream>>>(xhi, xlo, wt_hi, wt_lo, bv, nullptr, vth, vtl);

    // x-split dead from here: ch/cl overwrite xhi/xlo
    attn_pass1<<<dim3(S_ / 128, H_, B_), 256, 0, stream>>>(qh, ql, kh, kl, vth, vtl,
                                                           swp, ch, cl, invl);

    attn_mean<<<dim3(S_ / 128, S_ / 128, B_), 256, 0, stream>>>(qh, ql, kh, kl,
                                                                swp, invl, amean);

    split_tw<<<gt, 256, 0, stream>>>(Wo, wt_hi, wt_lo);
    gemm_mfma<0><<<gg, 256, 0, stream>>>(ch, cl, wt_hi, wt_lo, bo, outp, nullptr, nullptr);
}

// Round 9
// 510.206 us; speedup vs baseline: 1.1804x; 1.1804x over previous
//
#include <hip/hip_runtime.h>

#define B_ 2
#define S_ 2048
#define E_ 1024
#define H_ 16
#define DH_ 64
#define HID_ 256
#define M_ (B_*S_)

typedef __attribute__((ext_vector_type(8))) short s16x8;
typedef __attribute__((ext_vector_type(4))) float f32x4;
typedef unsigned int u32;
typedef unsigned short u16;
typedef u32 __attribute__((address_space(1))) gu32;
typedef u32 __attribute__((address_space(3))) lu32;

#define MFMA_B16(a,b,c) __builtin_amdgcn_mfma_f32_16x16x32_bf16((a),(b),(c),0,0,0)

__device__ __forceinline__ f32x4 fzero() { f32x4 z = {0.f, 0.f, 0.f, 0.f}; return z; }

// round-to-nearest-even fp32 -> bf16
__device__ __forceinline__ u16 f2bf(float x) {
    u32 u = __float_as_uint(x);
    u32 r = u + 0x7FFFu + ((u >> 16) & 1u);
    return (u16)(r >> 16);
}
__device__ __forceinline__ float bf2f(u16 b) {
    return __uint_as_float(((u32)b) << 16);
}
// per-lane 16B global -> LDS at (wave-uniform base)+lane*16
__device__ __forceinline__ void gload16(const void* gsrc, void* ldst) {
    __builtin_amdgcn_global_load_lds((const gu32*)gsrc, (lu32*)ldst, 16, 0, 0);
}
__device__ __forceinline__ s16x8 lds_frag(const u16* base, int byt) {
    return *(const s16x8*)((const char*)base + byt);
}

// ------------------------------------------------------------- stub
__global__ __launch_bounds__(256)
void zfill(float* __restrict__ out, int n)
{
    const int i = blockIdx.x * 256 + threadIdx.x;
    if (i < n) out[i] = 0.f;
}

// ---------------------------------------------------------------- gate
__global__ __launch_bounds__(256)
void gate_kernel(const float* __restrict__ sync_f,
                 const float* __restrict__ Ws1, const float* __restrict__ bs1,
                 const float* __restrict__ Ws2, const float* __restrict__ bs2,
                 float* __restrict__ sw)
{
    __shared__ float xs[E_];
    __shared__ float hid[HID_];
    const int b = blockIdx.x, t = threadIdx.x;
    for (int i = t; i < E_; i += 256) xs[i] = sync_f[b * E_ + i];
    __syncthreads();
    float acc = bs1[t];
    for (int k = 0; k < E_; ++k) acc = fmaf(xs[k], Ws1[k * HID_ + t], acc);
    hid[t] = fmaxf(acc, 0.f);
    __syncthreads();
    if (t < H_) {
        float a = bs2[t];
        for (int k = 0; k < HID_; ++k) a = fmaf(hid[k], Ws2[k * H_ + t], a);
        sw[b * H_ + t] = 1.f / (1.f + __expf(-a));
    }
}

// ------------------------------------------------------------ split x
__global__ __launch_bounds__(256)
void split_x(const float* __restrict__ X, u16* __restrict__ Xhi, u16* __restrict__ Xlo)
{
    const int i = blockIdx.x * 256 + threadIdx.x;
    if (i >= M_ * E_ / 8) return;
    const float4 a = ((const float4*)X)[2 * i];
    const float4 bq = ((const float4*)X)[2 * i + 1];
    float v[8] = {a.x, a.y, a.z, a.w, bq.x, bq.y, bq.z, bq.w};
    s16x8 h, l;
#pragma unroll
    for (int e = 0; e < 8; ++e) {
        u16 hb = f2bf(v[e]);
        h[e] = (short)hb;
        l[e] = (short)f2bf(v[e] - bf2f(hb));
    }
    ((s16x8*)Xhi)[i] = h;
    ((s16x8*)Xlo)[i] = l;
}

// ---------------------------------------------- split + transpose W
__global__ __launch_bounds__(256)
void split_tw(const float* __restrict__ W, u16* __restrict__ Thi, u16* __restrict__ Tlo)
{
    __shared__ float t[64][65];
    const int k0 = blockIdx.y * 64;
    const int n0 = blockIdx.x * 64;
    const int tid = threadIdx.x;
    const int rr = tid >> 4;
    const int cc = (tid & 15) * 4;
#pragma unroll
    for (int p = 0; p < 4; ++p) {
        float4 v = *(const float4*)&W[(size_t)(k0 + p * 16 + rr) * E_ + n0 + cc];
        t[p * 16 + rr][cc + 0] = v.x;
        t[p * 16 + rr][cc + 1] = v.y;
        t[p * 16 + rr][cc + 2] = v.z;
        t[p * 16 + rr][cc + 3] = v.w;
    }
    __syncthreads();
    const int on = tid >> 2;
    const int ok = (tid & 3) * 16;
    s16x8 h0, h1, l0, l1;
#pragma unroll
    for (int j = 0; j < 8; ++j) {
        float v = t[ok + j][on];
        u16 hb = f2bf(v);
        h0[j] = (short)hb; l0[j] = (short)f2bf(v - bf2f(hb));
        float v2 = t[ok + 8 + j][on];
        u16 hb2 = f2bf(v2);
        h1[j] = (short)hb2; l1[j] = (short)f2bf(v2 - bf2f(hb2));
    }
    size_t o = (size_t)(n0 + on) * E_ + k0 + ok;
    *(s16x8*)&Thi[o] = h0;  *(s16x8*)&Thi[o + 8] = h1;
    *(s16x8*)&Tlo[o] = l0;  *(s16x8*)&Tlo[o + 8] = l1;
}

// ------------------------------------------------- split-bf16 MFMA GEMM
// v2: 8 waves (512 thr), wave = 32x64 sub-tile, double-buffered LDS,
// single __syncthreads per K-step with stage-at-top prefetch (2-phase:
// implicit vmcnt(0) drain lands one full compute-phase after issue).
template<int MODE>
__global__ __launch_bounds__(512)
void gemm_mfma(const u16* __restrict__ Ahi, const u16* __restrict__ Alo,
               const u16* __restrict__ Bhi, const u16* __restrict__ Blo,
               const float* __restrict__ bias,
               float* __restrict__ OutF, u16* __restrict__ OutHi, u16* __restrict__ OutLo)
{
    __shared__ u16 lA[2][2][128 * 32];   // [buf][hl] 8KB each -> 32KB
    __shared__ u16 lB[2][2][128 * 32];   // 32KB
    const int m0 = blockIdx.y * 128, n0 = blockIdx.x * 128;
    const int tid = threadIdx.x;
    const int w = tid >> 6, l = tid & 63;
    const int l15 = l & 15, l4 = l >> 4;
    const int wm = w >> 1, wn = w & 1;       // wm 0..3 (32-row strips), wn 0..1 (64-col)

    // staging: 4 tiles x 8KB over 512 threads = 4 gload16/thread
    auto stage = [&](int k0, int buf) {
#pragma unroll
        for (int jj = 0; jj < 4; ++jj) {
            const int seg = w * 4 + jj, tt = seg >> 3, q = seg & 7;
            const int r = q * 16 + (l >> 2);
            const int g = (l & 3) ^ ((r >> 1) & 3);
            const u16* src;
            if (tt == 0)      src = Ahi + (size_t)(m0 + r) * E_ + k0 + 8 * g;
            else if (tt == 1) src = Alo + (size_t)(m0 + r) * E_ + k0 + 8 * g;
            else if (tt == 2) src = Bhi + (size_t)(n0 + r) * E_ + k0 + 8 * g;
            else              src = Blo + (size_t)(n0 + r) * E_ + k0 + 8 * g;
            u16* base = (tt < 2) ? lA[buf][tt] : lB[buf][tt - 2];
            gload16(src, (char*)base + q * 1024);
        }
    };

    f32x4 acc[2][4];
#pragma unroll
    for (int i = 0; i < 2; ++i)
#pragma unroll
        for (int j = 0; j < 4; ++j) acc[i][j] = fzero();

    stage(0, 0);
    for (int ks = 0; ks < 32; ++ks) {
        const int buf = ks & 1;
        __syncthreads();                 // stage(ks) visible; buf^1 free
        if (ks + 1 < 32) stage((ks + 1) * 32, buf ^ 1);

        s16x8 af[2][2];
#pragma unroll
        for (int hl = 0; hl < 2; ++hl)
#pragma unroll
            for (int mf = 0; mf < 2; ++mf) {
                const int row = wm * 32 + mf * 16 + l15;
                af[hl][mf] = lds_frag(lA[buf][hl], row * 64 + ((l4 ^ ((row >> 1) & 3)) << 4));
            }
#pragma unroll
        for (int nf = 0; nf < 4; ++nf) {
            const int rowb = wn * 64 + nf * 16 + l15;
            const int byt = rowb * 64 + ((l4 ^ ((rowb >> 1) & 3)) << 4);
            s16x8 b0 = lds_frag(lB[buf][0], byt);
            s16x8 b1 = lds_frag(lB[buf][1], byt);
#pragma unroll
            for (int mf = 0; mf < 2; ++mf) {
                acc[mf][nf] = MFMA_B16(af[0][mf], b0, acc[mf][nf]);
                acc[mf][nf] = MFMA_B16(af[0][mf], b1, acc[mf][nf]);
                acc[mf][nf] = MFMA_B16(af[1][mf], b0, acc[mf][nf]);
            }
        }
    }

    // epilogue: D layout col=l&15, row=(l>>4)*4+reg  [m89-verified]
#pragma unroll
    for (int mf = 0; mf < 2; ++mf)
#pragma unroll
        for (int nf = 0; nf < 4; ++nf) {
            const int n = n0 + wn * 64 + nf * 16 + l15;
            const float bb = bias[n];
#pragma unroll
            for (int rr = 0; rr < 4; ++rr) {
                const int m = m0 + wm * 32 + mf * 16 + l4 * 4 + rr;
                const float v = acc[mf][nf][rr] + bb;
                if (MODE == 0) {
                    OutF[(size_t)m * E_ + n] = v;
                } else {
                    const int bat = m >> 11, s = m & (S_ - 1);
                    const int hh = n >> 6, dh = n & 63;
                    const size_t o = (MODE == 1)
                        ? (((size_t)(bat * H_ + hh) * S_ + s) * DH_ + dh)
                        : (((size_t)(bat * H_ + hh) * DH_ + dh) * S_ + s);
                    const u16 hb = f2bf(v);
                    OutHi[o] = hb;
                    OutLo[o] = f2bf(v - bf2f(hb));
                }
            }
        }
}

// ---------------------------------------------------- attention pass 1
// v2: 256 q-rows/block, 8 waves x 32-row strips (per-wave code = v1),
// double-buffered K/V (64KB) + wave-private lP (64KB) = 128KB LDS,
// single __syncthreads per j-tile, stage-at-top prefetch.
__global__ __launch_bounds__(512)
void attn_pass1(const u16* __restrict__ qhi, const u16* __restrict__ qlo,
                const u16* __restrict__ khi, const u16* __restrict__ klo,
                const u16* __restrict__ vthi, const u16* __restrict__ vtlo,
                const float* __restrict__ sw,
                u16* __restrict__ ctxhi, u16* __restrict__ ctxlo,
                float* __restrict__ invl)
{
    __shared__ u16 lK[2][2][64 * 64];   // [buf][hl] 8KB -> 32KB
    __shared__ u16 lV[2][2][64 * 64];   // 32KB
    __shared__ float lP[256 * 64];      // 64KB, wave-private 32-row strips
    const int b = blockIdx.z, h = blockIdx.y, i0 = blockIdx.x * 256;
    const int tid = threadIdx.x;
    const int w = tid >> 6, l = tid & 63;
    const int l15 = l & 15, l4 = l >> 4;
    const size_t bh = (size_t)(b * H_ + h);
    const float scl = sw[b * H_ + h] * 0.125f;

    // staging: 4 tiles x 8KB over 512 threads = 4 gload16/thread
    auto stage_kv = [&](int j0, int buf) {
#pragma unroll
        for (int jj = 0; jj < 4; ++jj) {
            const int seg = w * 4 + jj, tt = seg >> 3, q = seg & 7;
            const int r = q * 8 + (l >> 3);
            const int g = (l & 7) ^ (r & 7);
            const u16* src;
            if (tt == 0)      src = khi  + (bh * S_ + j0 + r) * DH_ + 8 * g;
            else if (tt == 1) src = klo  + (bh * S_ + j0 + r) * DH_ + 8 * g;
            else if (tt == 2) src = vthi + (bh * DH_ + r) * S_ + j0 + 8 * g;
            else              src = vtlo + (bh * DH_ + r) * S_ + j0 + 8 * g;
            u16* base = (tt < 2) ? lK[buf][tt] : lV[buf][tt - 2];
            gload16(src, (char*)base + q * 1024);
        }
    };

    // Q fragments, resident: [hl][rf][kc]
    s16x8 qf[2][2][2];
#pragma unroll
    for (int hl = 0; hl < 2; ++hl)
#pragma unroll
        for (int rf = 0; rf < 2; ++rf)
#pragma unroll
            for (int kc = 0; kc < 2; ++kc) {
                const int row = i0 + w * 32 + rf * 16 + l15;
                const u16* src = (hl ? qlo : qhi) + (bh * S_ + row) * DH_ + kc * 32 + 8 * l4;
                qf[hl][rf][kc] = *(const s16x8*)src;
            }

    f32x4 cacc[2][4];
    float l_acc[2][4];
#pragma unroll
    for (int rf = 0; rf < 2; ++rf) {
#pragma unroll
        for (int df = 0; df < 4; ++df) cacc[rf][df] = fzero();
#pragma unroll
        for (int rr = 0; rr < 4; ++rr) l_acc[rf][rr] = 0.f;
    }

    stage_kv(0, 0);
    for (int jt = 0; jt < S_ / 64; ++jt) {
        const int buf = jt & 1;
        __syncthreads();                 // stage(jt) visible; buf^1 free
        if (jt + 1 < S_ / 64) stage_kv((jt + 1) * 64, buf ^ 1);

        // ---- QK^T (3-pass split) ----
        f32x4 p[2][4];
#pragma unroll
        for (int rf = 0; rf < 2; ++rf)
#pragma unroll
            for (int nf = 0; nf < 4; ++nf) p[rf][nf] = fzero();
#pragma unroll
        for (int kc = 0; kc < 2; ++kc) {
            s16x8 kb[2][4];
#pragma unroll
            for (int hl = 0; hl < 2; ++hl)
#pragma unroll
                for (int nf = 0; nf < 4; ++nf) {
                    const int j = nf * 16 + l15;
                    kb[hl][nf] = lds_frag(lK[buf][hl],
                        j * 128 + (((kc * 4 + l4) ^ (j & 7)) << 4));
                }
#pragma unroll
            for (int rf = 0; rf < 2; ++rf)
#pragma unroll
                for (int nf = 0; nf < 4; ++nf) {
                    p[rf][nf] = MFMA_B16(qf[0][rf][kc], kb[0][nf], p[rf][nf]);
                    p[rf][nf] = MFMA_B16(qf[0][rf][kc], kb[1][nf], p[rf][nf]);
                    p[rf][nf] = MFMA_B16(qf[1][rf][kc], kb[0][nf], p[rf][nf]);
                }
        }
        // ---- exp + l accumulation + P -> LDS (wave-private rows) ----
#pragma unroll
        for (int rf = 0; rf < 2; ++rf)
#pragma unroll
            for (int nf = 0; nf < 4; ++nf) {
                const int jcol = nf * 16 + l15;
#pragma unroll
                for (int rr = 0; rr < 4; ++rr) {
                    const float e = __expf(p[rf][nf][rr] * scl);
                    l_acc[rf][rr] += e;
                    const int irow = w * 32 + rf * 16 + l4 * 4 + rr;
                    const int byt = irow * 256 +
                        ((((jcol >> 2) ^ ((irow >> 1) & 7)) << 4) | ((jcol & 3) << 2));
                    *(float*)((char*)lP + byt) = e;
                }
            }
        // ---- PV (3-pass split) ----
#pragma unroll
        for (int kc = 0; kc < 2; ++kc) {
            s16x8 vb[2][4];
#pragma unroll
            for (int hl = 0; hl < 2; ++hl)
#pragma unroll
                for (int df = 0; df < 4; ++df) {
                    const int d = df * 16 + l15;
                    vb[hl][df] = lds_frag(lV[buf][hl],
                        d * 128 + (((kc * 4 + l4) ^ (d & 7)) << 4));
                }
#pragma unroll
            for (int rf = 0; rf < 2; ++rf) {
                const int irow = w * 32 + rf * 16 + l15;
                const int msk = (irow >> 1) & 7;
                float pv8[8];
#pragma unroll
                for (int hh = 0; hh < 2; ++hh) {
                    const int slot = kc * 8 + 2 * l4 + hh;
                    const f32x4 t4 = *(const f32x4*)((const char*)lP +
                                        irow * 256 + ((slot ^ msk) << 4));
                    pv8[hh * 4 + 0] = t4[0]; pv8[hh * 4 + 1] = t4[1];
                    pv8[hh * 4 + 2] = t4[2]; pv8[hh * 4 + 3] = t4[3];
                }
                s16x8 ph, pl;
#pragma unroll
                for (int e = 0; e < 8; ++e) {
                    const u16 hb = f2bf(pv8[e]);
                    ph[e] = (short)hb;
                    pl[e] = (short)f2bf(pv8[e] - bf2f(hb));
                }
#pragma unroll
                for (int df = 0; df < 4; ++df) {
                    cacc[rf][df] = MFMA_B16(ph, vb[0][df], cacc[rf][df]);
                    cacc[rf][df] = MFMA_B16(ph, vb[1][df], cacc[rf][df]);
                    cacc[rf][df] = MFMA_B16(pl, vb[0][df], cacc[rf][df]);
                }
            }
        }
    }

    // reduce l over the 16 col-lanes
#pragma unroll
    for (int rf = 0; rf < 2; ++rf)
#pragma unroll
        for (int rr = 0; rr < 4; ++rr) {
#pragma unroll
            for (int off = 1; off < 16; off <<= 1)
                l_acc[rf][rr] += __shfl_xor(l_acc[rf][rr], off);
        }
#pragma unroll
    for (int rf = 0; rf < 2; ++rf)
#pragma unroll
        for (int rr = 0; rr < 4; ++rr) {
            const float inv = 1.f / l_acc[rf][rr];
            const int srow = i0 + w * 32 + rf * 16 + l4 * 4 + rr;
            if (l15 == 0) invl[bh * S_ + srow] = inv;
#pragma unroll
            for (int df = 0; df < 4; ++df) {
                const float v = cacc[rf][df][rr] * inv;
                const size_t o = ((size_t)b * S_ + srow) * E_ + h * DH_ + df * 16 + l15;
                const u16 hb = f2bf(v);
                ctxhi[o] = hb;
                ctxlo[o] = f2bf(v - bf2f(hb));
            }
        }
}

// ---------------------------------------------------- attention mean
// v2: Q fragments loaded direct to registers (no lQ staging), K tile
// double-buffered (64KB), single __syncthreads per head + prefetch.
__global__ __launch_bounds__(256)
void attn_mean(const u16* __restrict__ qhi, const u16* __restrict__ qlo,
               const u16* __restrict__ khi, const u16* __restrict__ klo,
               const float* __restrict__ sw, const float* __restrict__ invl,
               float* __restrict__ amean)
{
    __shared__ u16 lKm[2][2][128 * 64];   // [buf][hl] 16KB -> 64KB
    const int b = blockIdx.z, i0 = blockIdx.y * 128, j0 = blockIdx.x * 128;
    const int tid = threadIdx.x;
    const int w = tid >> 6, l = tid & 63;
    const int l15 = l & 15, l4 = l >> 4;

    auto stage_k = [&](int h, int buf) {
        const size_t bh = (size_t)(b * H_ + h);
#pragma unroll
        for (int jj = 0; jj < 8; ++jj) {
            const int seg = w * 8 + jj, tt = seg >> 4, q = seg & 15;
            const int r = q * 8 + (l >> 3);
            const int g = (l & 7) ^ (r & 7);
            const u16* src = (tt ? klo : khi) + (bh * S_ + j0 + r) * DH_ + 8 * g;
            gload16(src, (char*)lKm[buf][tt] + q * 1024);
        }
    };

    f32x4 acc[2][8];
#pragma unroll
    for (int rf = 0; rf < 2; ++rf)
#pragma unroll
        for (int nf = 0; nf < 8; ++nf) acc[rf][nf] = fzero();

    stage_k(0, 0);
    for (int h = 0; h < H_; ++h) {
        const int buf = h & 1;
        __syncthreads();                 // stage(h) visible; buf^1 free
        if (h + 1 < H_) stage_k(h + 1, buf ^ 1);

        const size_t bh = (size_t)(b * H_ + h);
        const float scl = sw[b * H_ + h] * 0.125f;

        // Q fragments direct from global: [hl][rf][kc]
        s16x8 qa[2][2][2];
#pragma unroll
        for (int hl = 0; hl < 2; ++hl)
#pragma unroll
            for (int rf = 0; rf < 2; ++rf)
#pragma unroll
                for (int kc = 0; kc < 2; ++kc) {
                    const int row = i0 + w * 32 + rf * 16 + l15;
                    const u16* src = (hl ? qlo : qhi) + (bh * S_ + row) * DH_
                                     + kc * 32 + 8 * l4;
                    qa[hl][rf][kc] = *(const s16x8*)src;
                }
        float ivl[2][4];
#pragma unroll
        for (int rf = 0; rf < 2; ++rf)
#pragma unroll
            for (int rr = 0; rr < 4; ++rr)
                ivl[rf][rr] = invl[bh * S_ + i0 + w * 32 + rf * 16 + l4 * 4 + rr];

        f32x4 sc[2][8];
#pragma unroll
        for (int rf = 0; rf < 2; ++rf)
#pragma unroll
            for (int nf = 0; nf < 8; ++nf) sc[rf][nf] = fzero();
#pragma unroll
        for (int kc = 0; kc < 2; ++kc) {
#pragma unroll
            for (int nf = 0; nf < 8; ++nf) {
                const int j = nf * 16 + l15;
                const int byt = j * 128 + (((kc * 4 + l4) ^ (j & 7)) << 4);
                const s16x8 kb0 = lds_frag(lKm[buf][0], byt);
                const s16x8 kb1 = lds_frag(lKm[buf][1], byt);
#pragma unroll
                for (int rf = 0; rf < 2; ++rf) {
                    sc[rf][nf] = MFMA_B16(qa[0][rf][kc], kb0, sc[rf][nf]);
                    sc[rf][nf] = MFMA_B16(qa[0][rf][kc], kb1, sc[rf][nf]);
                    sc[rf][nf] = MFMA_B16(qa[1][rf][kc], kb0, sc[rf][nf]);
                }
            }
        }
#pragma unroll
        for (int rf = 0; rf < 2; ++rf)
#pragma unroll
            for (int nf = 0; nf < 8; ++nf)
#pragma unroll
                for (int rr = 0; rr < 4; ++rr)
                    acc[rf][nf][rr] = fmaf(__expf(sc[rf][nf][rr] * scl), ivl[rf][rr],
                                           acc[rf][nf][rr]);
    }

#pragma unroll
    for (int rf = 0; rf < 2; ++rf)
#pragma unroll
        for (int nf = 0; nf < 8; ++nf)
#pragma unroll
            for (int rr = 0; rr < 4; ++rr) {
                const int row = i0 + w * 32 + rf * 16 + l4 * 4 + rr;
                amean[((size_t)b * S_ + row) * S_ + j0 + nf * 16 + l15] =
                    acc[rf][nf][rr] * (1.0f / H_);
            }
}

// ----------------------------------------------------------------------
extern "C" void kernel_launch(void* const* d_in, const int* in_sizes, int n_in,
                              void* d_out, int out_size, void* d_ws, size_t ws_size,
                              hipStream_t stream) {
    (void)in_sizes; (void)n_in;
    const float* x     = (const float*)d_in[0];
    const float* syncf = (const float*)d_in[1];
    const float* Wq    = (const float*)d_in[2];
    const float* bq    = (const float*)d_in[3];
    const float* Wk    = (const float*)d_in[4];
    const float* bk    = (const float*)d_in[5];
    const float* Wv    = (const float*)d_in[6];
    const float* bv    = (const float*)d_in[7];
    const float* Ws1   = (const float*)d_in[8];
    const float* bs1   = (const float*)d_in[9];
    const float* Ws2   = (const float*)d_in[10];
    const float* bs2   = (const float*)d_in[11];
    const float* Wo    = (const float*)d_in[12];
    const float* bo    = (const float*)d_in[13];

    float* outp  = (float*)d_out;
    float* amean = outp + (size_t)M_ * E_;

    char* p = (char*)d_ws;
    auto alloc = [&](size_t bytes) {
        char* r = p; p += (bytes + 255) & ~(size_t)255; return r;
    };
    const size_t SZ_ME  = (size_t)M_ * E_ * 2;
    const size_t SZ_W   = (size_t)E_ * E_ * 2;
    float* swp  = (float*)alloc(128);
    u16* xhi    = (u16*)alloc(SZ_ME);                 // later: ch
    u16* xlo    = (u16*)alloc(SZ_ME);                 // later: cl
    u16* wt_hi  = (u16*)alloc(SZ_W);                  // shared for all 4 weights
    u16* wt_lo  = (u16*)alloc(SZ_W);
    u16* qh     = (u16*)alloc(SZ_ME);
    u16* ql     = (u16*)alloc(SZ_ME);
    u16* kh     = (u16*)alloc(SZ_ME);
    u16* kl     = (u16*)alloc(SZ_ME);
    u16* vth    = (u16*)alloc(SZ_ME);
    u16* vtl    = (u16*)alloc(SZ_ME);
    float* invl = (float*)alloc((size_t)B_ * H_ * S_ * 4);

    const size_t need = (size_t)(p - (char*)d_ws);
    if (ws_size < need) {
        zfill<<<dim3((out_size + 255) / 256), 256, 0, stream>>>(outp, out_size);
        return;
    }

    u16* ch = xhi;
    u16* cl = xlo;

    gate_kernel<<<dim3(B_), 256, 0, stream>>>(syncf, Ws1, bs1, Ws2, bs2, swp);
    split_x<<<dim3(M_ * E_ / 8 / 256), 256, 0, stream>>>(x, xhi, xlo);

    dim3 gt(16, 16);
    dim3 gg(E_ / 128, M_ / 128);
    split_tw<<<gt, 256, 0, stream>>>(Wq, wt_hi, wt_lo);
    gemm_mfma<1><<<gg, 512, 0, stream>>>(xhi, xlo, wt_hi, wt_lo, bq, nullptr, qh, ql);
    split_tw<<<gt, 256, 0, stream>>>(Wk, wt_hi, wt_lo);
    gemm_mfma<1><<<gg, 512, 0, stream>>>(xhi, xlo, wt_hi, wt_lo, bk, nullptr, kh, kl);
    split_tw<<<gt, 256, 0, stream>>>(Wv, wt_hi, wt_lo);
    gemm_mfma<2><<<gg, 512, 0, stream>>>(xhi, xlo, wt_hi, wt_lo, bv, nullptr, vth, vtl);

    // x-split dead from here: ch/cl overwrite xhi/xlo
    attn_pass1<<<dim3(S_ / 256, H_, B_), 512, 0, stream>>>(qh, ql, kh, kl, vth, vtl,
                                                           swp, ch, cl, invl);

    attn_mean<<<dim3(S_ / 128, S_ / 128, B_), 256, 0, stream>>>(qh, ql, kh, kl,
                                                                swp, invl, amean);

    split_tw<<<gt, 256, 0, stream>>>(Wo, wt_hi, wt_lo);
    gemm_mfma<0><<<gg, 512, 0, stream>>>(ch, cl, wt_hi, wt_lo, bo, outp, nullptr, nullptr);
}

// Round 10
// 491.917 us; speedup vs baseline: 1.2243x; 1.0372x over previous
//
#include <hip/hip_runtime.h>

#define B_ 2
#define S_ 2048
#define E_ 1024
#define H_ 16
#define DH_ 64
#define HID_ 256
#define M_ (B_*S_)

typedef __attribute__((ext_vector_type(8))) short s16x8;
typedef __attribute__((ext_vector_type(4))) float f32x4;
typedef unsigned int u32;
typedef unsigned short u16;
typedef u32 __attribute__((address_space(1))) gu32;
typedef u32 __attribute__((address_space(3))) lu32;

#define MFMA_B16(a,b,c) __builtin_amdgcn_mfma_f32_16x16x32_bf16((a),(b),(c),0,0,0)

__device__ __forceinline__ f32x4 fzero() { f32x4 z = {0.f, 0.f, 0.f, 0.f}; return z; }

// round-to-nearest-even fp32 -> bf16
__device__ __forceinline__ u16 f2bf(float x) {
    u32 u = __float_as_uint(x);
    u32 r = u + 0x7FFFu + ((u >> 16) & 1u);
    return (u16)(r >> 16);
}
__device__ __forceinline__ float bf2f(u16 b) {
    return __uint_as_float(((u32)b) << 16);
}
// per-lane 16B global -> LDS at (wave-uniform base)+lane*16
__device__ __forceinline__ void gload16(const void* gsrc, void* ldst) {
    __builtin_amdgcn_global_load_lds((const gu32*)gsrc, (lu32*)ldst, 16, 0, 0);
}
__device__ __forceinline__ s16x8 lds_frag(const u16* base, int byt) {
    return *(const s16x8*)((const char*)base + byt);
}

// ------------------------------------------------------------- stub
__global__ __launch_bounds__(256)
void zfill(float* __restrict__ out, int n)
{
    const int i = blockIdx.x * 256 + threadIdx.x;
    if (i < n) out[i] = 0.f;
}

// ---------------------------------------------------------------- gate
__global__ __launch_bounds__(256)
void gate_kernel(const float* __restrict__ sync_f,
                 const float* __restrict__ Ws1, const float* __restrict__ bs1,
                 const float* __restrict__ Ws2, const float* __restrict__ bs2,
                 float* __restrict__ sw)
{
    __shared__ float xs[E_];
    __shared__ float hid[HID_];
    const int b = blockIdx.x, t = threadIdx.x;
    for (int i = t; i < E_; i += 256) xs[i] = sync_f[b * E_ + i];
    __syncthreads();
    float acc = bs1[t];
    for (int k = 0; k < E_; ++k) acc = fmaf(xs[k], Ws1[k * HID_ + t], acc);
    hid[t] = fmaxf(acc, 0.f);
    __syncthreads();
    if (t < H_) {
        float a = bs2[t];
        for (int k = 0; k < HID_; ++k) a = fmaf(hid[k], Ws2[k * H_ + t], a);
        sw[b * H_ + t] = 1.f / (1.f + __expf(-a));
    }
}

// ------------------------------------------------------------ split x
__global__ __launch_bounds__(256)
void split_x(const float* __restrict__ X, u16* __restrict__ Xhi, u16* __restrict__ Xlo)
{
    const int i = blockIdx.x * 256 + threadIdx.x;
    if (i >= M_ * E_ / 8) return;
    const float4 a = ((const float4*)X)[2 * i];
    const float4 bq = ((const float4*)X)[2 * i + 1];
    float v[8] = {a.x, a.y, a.z, a.w, bq.x, bq.y, bq.z, bq.w};
    s16x8 h, l;
#pragma unroll
    for (int e = 0; e < 8; ++e) {
        u16 hb = f2bf(v[e]);
        h[e] = (short)hb;
        l[e] = (short)f2bf(v[e] - bf2f(hb));
    }
    ((s16x8*)Xhi)[i] = h;
    ((s16x8*)Xlo)[i] = l;
}

// ---------------------------------------------- split + transpose W
__global__ __launch_bounds__(256)
void split_tw(const float* __restrict__ W, u16* __restrict__ Thi, u16* __restrict__ Tlo)
{
    __shared__ float t[64][65];
    const int k0 = blockIdx.y * 64;
    const int n0 = blockIdx.x * 64;
    const int tid = threadIdx.x;
    const int rr = tid >> 4;
    const int cc = (tid & 15) * 4;
#pragma unroll
    for (int p = 0; p < 4; ++p) {
        float4 v = *(const float4*)&W[(size_t)(k0 + p * 16 + rr) * E_ + n0 + cc];
        t[p * 16 + rr][cc + 0] = v.x;
        t[p * 16 + rr][cc + 1] = v.y;
        t[p * 16 + rr][cc + 2] = v.z;
        t[p * 16 + rr][cc + 3] = v.w;
    }
    __syncthreads();
    const int on = tid >> 2;
    const int ok = (tid & 3) * 16;
    s16x8 h0, h1, l0, l1;
#pragma unroll
    for (int j = 0; j < 8; ++j) {
        float v = t[ok + j][on];
        u16 hb = f2bf(v);
        h0[j] = (short)hb; l0[j] = (short)f2bf(v - bf2f(hb));
        float v2 = t[ok + 8 + j][on];
        u16 hb2 = f2bf(v2);
        h1[j] = (short)hb2; l1[j] = (short)f2bf(v2 - bf2f(hb2));
    }
    size_t o = (size_t)(n0 + on) * E_ + k0 + ok;
    *(s16x8*)&Thi[o] = h0;  *(s16x8*)&Thi[o + 8] = h1;
    *(s16x8*)&Tlo[o] = l0;  *(s16x8*)&Tlo[o + 8] = l1;
}

// ------------------------------------------------- split-bf16 MFMA GEMM
// v3: v2 + XCD-aware block swizzle (T1). Grid (8,32); HW round-robins
// linear id over 8 XCDs, so give each XCD a 4x8 (n x m) panel rectangle:
// per-XCD reads 2MB B + 4MB A instead of 0.5MB B + 16MB A (A was
// streamed 8x chip-wide). Bijection: (k8,sq) <-> (nb,mb).
template<int MODE>
__global__ __launch_bounds__(512)
void gemm_mfma(const u16* __restrict__ Ahi, const u16* __restrict__ Alo,
               const u16* __restrict__ Bhi, const u16* __restrict__ Blo,
               const float* __restrict__ bias,
               float* __restrict__ OutF, u16* __restrict__ OutHi, u16* __restrict__ OutLo)
{
    __shared__ u16 lA[2][2][128 * 32];   // [buf][hl] 8KB each -> 32KB
    __shared__ u16 lB[2][2][128 * 32];   // 32KB
    const int L = blockIdx.x + 8 * blockIdx.y;
    const int k8 = L & 7, sq = L >> 3;           // xcd, seq-on-xcd
    const int nb = (k8 & 1) * 4 + (sq & 3);      // n-block 0..7
    const int mb = (k8 >> 1) * 8 + (sq >> 2);    // m-block 0..31
    const int m0 = mb * 128, n0 = nb * 128;
    const int tid = threadIdx.x;
    const int w = tid >> 6, l = tid & 63;
    const int l15 = l & 15, l4 = l >> 4;
    const int wm = w >> 1, wn = w & 1;       // wm 0..3 (32-row strips), wn 0..1 (64-col)

    // staging: 4 tiles x 8KB over 512 threads = 4 gload16/thread
    auto stage = [&](int k0, int buf) {
#pragma unroll
        for (int jj = 0; jj < 4; ++jj) {
            const int seg = w * 4 + jj, tt = seg >> 3, q = seg & 7;
            const int r = q * 16 + (l >> 2);
            const int g = (l & 3) ^ ((r >> 1) & 3);
            const u16* src;
            if (tt == 0)      src = Ahi + (size_t)(m0 + r) * E_ + k0 + 8 * g;
            else if (tt == 1) src = Alo + (size_t)(m0 + r) * E_ + k0 + 8 * g;
            else if (tt == 2) src = Bhi + (size_t)(n0 + r) * E_ + k0 + 8 * g;
            else              src = Blo + (size_t)(n0 + r) * E_ + k0 + 8 * g;
            u16* base = (tt < 2) ? lA[buf][tt] : lB[buf][tt - 2];
            gload16(src, (char*)base + q * 1024);
        }
    };

    f32x4 acc[2][4];
#pragma unroll
    for (int i = 0; i < 2; ++i)
#pragma unroll
        for (int j = 0; j < 4; ++j) acc[i][j] = fzero();

    stage(0, 0);
    for (int ks = 0; ks < 32; ++ks) {
        const int buf = ks & 1;
        __syncthreads();                 // stage(ks) visible; buf^1 free
        if (ks + 1 < 32) stage((ks + 1) * 32, buf ^ 1);

        s16x8 af[2][2];
#pragma unroll
        for (int hl = 0; hl < 2; ++hl)
#pragma unroll
            for (int mf = 0; mf < 2; ++mf) {
                const int row = wm * 32 + mf * 16 + l15;
                af[hl][mf] = lds_frag(lA[buf][hl], row * 64 + ((l4 ^ ((row >> 1) & 3)) << 4));
            }
#pragma unroll
        for (int nf = 0; nf < 4; ++nf) {
            const int rowb = wn * 64 + nf * 16 + l15;
            const int byt = rowb * 64 + ((l4 ^ ((rowb >> 1) & 3)) << 4);
            s16x8 b0 = lds_frag(lB[buf][0], byt);
            s16x8 b1 = lds_frag(lB[buf][1], byt);
#pragma unroll
            for (int mf = 0; mf < 2; ++mf) {
                acc[mf][nf] = MFMA_B16(af[0][mf], b0, acc[mf][nf]);
                acc[mf][nf] = MFMA_B16(af[0][mf], b1, acc[mf][nf]);
                acc[mf][nf] = MFMA_B16(af[1][mf], b0, acc[mf][nf]);
            }
        }
    }

    // epilogue: D layout col=l&15, row=(l>>4)*4+reg  [m89-verified]
#pragma unroll
    for (int mf = 0; mf < 2; ++mf)
#pragma unroll
        for (int nf = 0; nf < 4; ++nf) {
            const int n = n0 + wn * 64 + nf * 16 + l15;
            const float bb = bias[n];
#pragma unroll
            for (int rr = 0; rr < 4; ++rr) {
                const int m = m0 + wm * 32 + mf * 16 + l4 * 4 + rr;
                const float v = acc[mf][nf][rr] + bb;
                if (MODE == 0) {
                    OutF[(size_t)m * E_ + n] = v;
                } else {
                    const int bat = m >> 11, s = m & (S_ - 1);
                    const int hh = n >> 6, dh = n & 63;
                    const size_t o = (MODE == 1)
                        ? (((size_t)(bat * H_ + hh) * S_ + s) * DH_ + dh)
                        : (((size_t)(bat * H_ + hh) * DH_ + dh) * S_ + s);
                    const u16 hb = f2bf(v);
                    OutHi[o] = hb;
                    OutLo[o] = f2bf(v - bf2f(hb));
                }
            }
        }
}

// ---------------------------------------------------- attention pass 1
// v3: v2 + XCD-aware swizzle (T1): 256 blocks = 8 XCDs x 4 heads x
// 8 q-blocks. All 8 q-blocks of one head land on ONE XCD -> K/V tiles
// fetched to that L2 once (blocks sweep j in near-lockstep; active
// window ~256KB). R9 showed FETCH=139MB from XCD dispersal.
__global__ __launch_bounds__(512)
void attn_pass1(const u16* __restrict__ qhi, const u16* __restrict__ qlo,
                const u16* __restrict__ khi, const u16* __restrict__ klo,
                const u16* __restrict__ vthi, const u16* __restrict__ vtlo,
                const float* __restrict__ sw,
                u16* __restrict__ ctxhi, u16* __restrict__ ctxlo,
                float* __restrict__ invl)
{
    __shared__ u16 lK[2][2][64 * 64];   // [buf][hl] 8KB -> 32KB
    __shared__ u16 lV[2][2][64 * 64];   // 32KB
    __shared__ float lP[256 * 64];      // 64KB, wave-private 32-row strips
    const int L = blockIdx.x + 8 * (blockIdx.y + 16 * blockIdx.z);
    const int k8 = L & 7, sq = L >> 3;       // xcd, seq-on-xcd (0..31)
    const int hy = k8 * 4 + (sq & 3);        // (b,h) index 0..31, 4 heads/XCD
    const int b = hy >> 4, h = hy & 15;
    const int i0 = (sq >> 2) * 256;          // q-block 0..7
    const int tid = threadIdx.x;
    const int w = tid >> 6, l = tid & 63;
    const int l15 = l & 15, l4 = l >> 4;
    const size_t bh = (size_t)(b * H_ + h);
    const float scl = sw[b * H_ + h] * 0.125f;

    // staging: 4 tiles x 8KB over 512 threads = 4 gload16/thread
    auto stage_kv = [&](int j0, int buf) {
#pragma unroll
        for (int jj = 0; jj < 4; ++jj) {
            const int seg = w * 4 + jj, tt = seg >> 3, q = seg & 7;
            const int r = q * 8 + (l >> 3);
            const int g = (l & 7) ^ (r & 7);
            const u16* src;
            if (tt == 0)      src = khi  + (bh * S_ + j0 + r) * DH_ + 8 * g;
            else if (tt == 1) src = klo  + (bh * S_ + j0 + r) * DH_ + 8 * g;
            else if (tt == 2) src = vthi + (bh * DH_ + r) * S_ + j0 + 8 * g;
            else              src = vtlo + (bh * DH_ + r) * S_ + j0 + 8 * g;
            u16* base = (tt < 2) ? lK[buf][tt] : lV[buf][tt - 2];
            gload16(src, (char*)base + q * 1024);
        }
    };

    // Q fragments, resident: [hl][rf][kc]
    s16x8 qf[2][2][2];
#pragma unroll
    for (int hl = 0; hl < 2; ++hl)
#pragma unroll
        for (int rf = 0; rf < 2; ++rf)
#pragma unroll
            for (int kc = 0; kc < 2; ++kc) {
                const int row = i0 + w * 32 + rf * 16 + l15;
                const u16* src = (hl ? qlo : qhi) + (bh * S_ + row) * DH_ + kc * 32 + 8 * l4;
                qf[hl][rf][kc] = *(const s16x8*)src;
            }

    f32x4 cacc[2][4];
    float l_acc[2][4];
#pragma unroll
    for (int rf = 0; rf < 2; ++rf) {
#pragma unroll
        for (int df = 0; df < 4; ++df) cacc[rf][df] = fzero();
#pragma unroll
        for (int rr = 0; rr < 4; ++rr) l_acc[rf][rr] = 0.f;
    }

    stage_kv(0, 0);
    for (int jt = 0; jt < S_ / 64; ++jt) {
        const int buf = jt & 1;
        __syncthreads();                 // stage(jt) visible; buf^1 free
        if (jt + 1 < S_ / 64) stage_kv((jt + 1) * 64, buf ^ 1);

        // ---- QK^T (3-pass split) ----
        f32x4 p[2][4];
#pragma unroll
        for (int rf = 0; rf < 2; ++rf)
#pragma unroll
            for (int nf = 0; nf < 4; ++nf) p[rf][nf] = fzero();
#pragma unroll
        for (int kc = 0; kc < 2; ++kc) {
            s16x8 kb[2][4];
#pragma unroll
            for (int hl = 0; hl < 2; ++hl)
#pragma unroll
                for (int nf = 0; nf < 4; ++nf) {
                    const int j = nf * 16 + l15;
                    kb[hl][nf] = lds_frag(lK[buf][hl],
                        j * 128 + (((kc * 4 + l4) ^ (j & 7)) << 4));
                }
#pragma unroll
            for (int rf = 0; rf < 2; ++rf)
#pragma unroll
                for (int nf = 0; nf < 4; ++nf) {
                    p[rf][nf] = MFMA_B16(qf[0][rf][kc], kb[0][nf], p[rf][nf]);
                    p[rf][nf] = MFMA_B16(qf[0][rf][kc], kb[1][nf], p[rf][nf]);
                    p[rf][nf] = MFMA_B16(qf[1][rf][kc], kb[0][nf], p[rf][nf]);
                }
        }
        // ---- exp + l accumulation + P -> LDS (wave-private rows) ----
#pragma unroll
        for (int rf = 0; rf < 2; ++rf)
#pragma unroll
            for (int nf = 0; nf < 4; ++nf) {
                const int jcol = nf * 16 + l15;
#pragma unroll
                for (int rr = 0; rr < 4; ++rr) {
                    const float e = __expf(p[rf][nf][rr] * scl);
                    l_acc[rf][rr] += e;
                    const int irow = w * 32 + rf * 16 + l4 * 4 + rr;
                    const int byt = irow * 256 +
                        ((((jcol >> 2) ^ ((irow >> 1) & 7)) << 4) | ((jcol & 3) << 2));
                    *(float*)((char*)lP + byt) = e;
                }
            }
        // ---- PV (3-pass split) ----
#pragma unroll
        for (int kc = 0; kc < 2; ++kc) {
            s16x8 vb[2][4];
#pragma unroll
            for (int hl = 0; hl < 2; ++hl)
#pragma unroll
                for (int df = 0; df < 4; ++df) {
                    const int d = df * 16 + l15;
                    vb[hl][df] = lds_frag(lV[buf][hl],
                        d * 128 + (((kc * 4 + l4) ^ (d & 7)) << 4));
                }
#pragma unroll
            for (int rf = 0; rf < 2; ++rf) {
                const int irow = w * 32 + rf * 16 + l15;
                const int msk = (irow >> 1) & 7;
                float pv8[8];
#pragma unroll
                for (int hh = 0; hh < 2; ++hh) {
                    const int slot = kc * 8 + 2 * l4 + hh;
                    const f32x4 t4 = *(const f32x4*)((const char*)lP +
                                        irow * 256 + ((slot ^ msk) << 4));
                    pv8[hh * 4 + 0] = t4[0]; pv8[hh * 4 + 1] = t4[1];
                    pv8[hh * 4 + 2] = t4[2]; pv8[hh * 4 + 3] = t4[3];
                }
                s16x8 ph, pl;
#pragma unroll
                for (int e = 0; e < 8; ++e) {
                    const u16 hb = f2bf(pv8[e]);
                    ph[e] = (short)hb;
                    pl[e] = (short)f2bf(pv8[e] - bf2f(hb));
                }
#pragma unroll
                for (int df = 0; df < 4; ++df) {
                    cacc[rf][df] = MFMA_B16(ph, vb[0][df], cacc[rf][df]);
                    cacc[rf][df] = MFMA_B16(ph, vb[1][df], cacc[rf][df]);
                    cacc[rf][df] = MFMA_B16(pl, vb[0][df], cacc[rf][df]);
                }
            }
        }
    }

    // reduce l over the 16 col-lanes
#pragma unroll
    for (int rf = 0; rf < 2; ++rf)
#pragma unroll
        for (int rr = 0; rr < 4; ++rr) {
#pragma unroll
            for (int off = 1; off < 16; off <<= 1)
                l_acc[rf][rr] += __shfl_xor(l_acc[rf][rr], off);
        }
#pragma unroll
    for (int rf = 0; rf < 2; ++rf)
#pragma unroll
        for (int rr = 0; rr < 4; ++rr) {
            const float inv = 1.f / l_acc[rf][rr];
            const int srow = i0 + w * 32 + rf * 16 + l4 * 4 + rr;
            if (l15 == 0) invl[bh * S_ + srow] = inv;
#pragma unroll
            for (int df = 0; df < 4; ++df) {
                const float v = cacc[rf][df][rr] * inv;
                const size_t o = ((size_t)b * S_ + srow) * E_ + h * DH_ + df * 16 + l15;
                const u16 hb = f2bf(v);
                ctxhi[o] = hb;
                ctxlo[o] = f2bf(v - bf2f(hb));
            }
        }
}

// ---------------------------------------------------- attention mean
// v2: Q fragments loaded direct to registers (no lQ staging), K tile
// double-buffered (64KB), single __syncthreads per head + prefetch.
// No swizzle: K-sharing blocks (same x,z; Dy=16 -> same L%8) already
// cluster on one XCD under round-robin dispatch.
__global__ __launch_bounds__(256)
void attn_mean(const u16* __restrict__ qhi, const u16* __restrict__ qlo,
               const u16* __restrict__ khi, const u16* __restrict__ klo,
               const float* __restrict__ sw, const float* __restrict__ invl,
               float* __restrict__ amean)
{
    __shared__ u16 lKm[2][2][128 * 64];   // [buf][hl] 16KB -> 64KB
    const int b = blockIdx.z, i0 = blockIdx.y * 128, j0 = blockIdx.x * 128;
    const int tid = threadIdx.x;
    const int w = tid >> 6, l = tid & 63;
    const int l15 = l & 15, l4 = l >> 4;

    auto stage_k = [&](int h, int buf) {
        const size_t bh = (size_t)(b * H_ + h);
#pragma unroll
        for (int jj = 0; jj < 8; ++jj) {
            const int seg = w * 8 + jj, tt = seg >> 4, q = seg & 15;
            const int r = q * 8 + (l >> 3);
            const int g = (l & 7) ^ (r & 7);
            const u16* src = (tt ? klo : khi) + (bh * S_ + j0 + r) * DH_ + 8 * g;
            gload16(src, (char*)lKm[buf][tt] + q * 1024);
        }
    };

    f32x4 acc[2][8];
#pragma unroll
    for (int rf = 0; rf < 2; ++rf)
#pragma unroll
        for (int nf = 0; nf < 8; ++nf) acc[rf][nf] = fzero();

    stage_k(0, 0);
    for (int h = 0; h < H_; ++h) {
        const int buf = h & 1;
        __syncthreads();                 // stage(h) visible; buf^1 free
        if (h + 1 < H_) stage_k(h + 1, buf ^ 1);

        const size_t bh = (size_t)(b * H_ + h);
        const float scl = sw[b * H_ + h] * 0.125f;

        // Q fragments direct from global: [hl][rf][kc]
        s16x8 qa[2][2][2];
#pragma unroll
        for (int hl = 0; hl < 2; ++hl)
#pragma unroll
            for (int rf = 0; rf < 2; ++rf)
#pragma unroll
                for (int kc = 0; kc < 2; ++kc) {
                    const int row = i0 + w * 32 + rf * 16 + l15;
                    const u16* src = (hl ? qlo : qhi) + (bh * S_ + row) * DH_
                                     + kc * 32 + 8 * l4;
                    qa[hl][rf][kc] = *(const s16x8*)src;
                }
        float ivl[2][4];
#pragma unroll
        for (int rf = 0; rf < 2; ++rf)
#pragma unroll
            for (int rr = 0; rr < 4; ++rr)
                ivl[rf][rr] = invl[bh * S_ + i0 + w * 32 + rf * 16 + l4 * 4 + rr];

        f32x4 sc[2][8];
#pragma unroll
        for (int rf = 0; rf < 2; ++rf)
#pragma unroll
            for (int nf = 0; nf < 8; ++nf) sc[rf][nf] = fzero();
#pragma unroll
        for (int kc = 0; kc < 2; ++kc) {
#pragma unroll
            for (int nf = 0; nf < 8; ++nf) {
                const int j = nf * 16 + l15;
                const int byt = j * 128 + (((kc * 4 + l4) ^ (j & 7)) << 4);
                const s16x8 kb0 = lds_frag(lKm[buf][0], byt);
                const s16x8 kb1 = lds_frag(lKm[buf][1], byt);
#pragma unroll
                for (int rf = 0; rf < 2; ++rf) {
                    sc[rf][nf] = MFMA_B16(qa[0][rf][kc], kb0, sc[rf][nf]);
                    sc[rf][nf] = MFMA_B16(qa[0][rf][kc], kb1, sc[rf][nf]);
                    sc[rf][nf] = MFMA_B16(qa[1][rf][kc], kb0, sc[rf][nf]);
                }
            }
        }
#pragma unroll
        for (int rf = 0; rf < 2; ++rf)
#pragma unroll
            for (int nf = 0; nf < 8; ++nf)
#pragma unroll
                for (int rr = 0; rr < 4; ++rr)
                    acc[rf][nf][rr] = fmaf(__expf(sc[rf][nf][rr] * scl), ivl[rf][rr],
                                           acc[rf][nf][rr]);
    }

#pragma unroll
    for (int rf = 0; rf < 2; ++rf)
#pragma unroll
        for (int nf = 0; nf < 8; ++nf)
#pragma unroll
            for (int rr = 0; rr < 4; ++rr) {
                const int row = i0 + w * 32 + rf * 16 + l4 * 4 + rr;
                amean[((size_t)b * S_ + row) * S_ + j0 + nf * 16 + l15] =
                    acc[rf][nf][rr] * (1.0f / H_);
            }
}

// ----------------------------------------------------------------------
extern "C" void kernel_launch(void* const* d_in, const int* in_sizes, int n_in,
                              void* d_out, int out_size, void* d_ws, size_t ws_size,
                              hipStream_t stream) {
    (void)in_sizes; (void)n_in;
    const float* x     = (const float*)d_in[0];
    const float* syncf = (const float*)d_in[1];
    const float* Wq    = (const float*)d_in[2];
    const float* bq    = (const float*)d_in[3];
    const float* Wk    = (const float*)d_in[4];
    const float* bk    = (const float*)d_in[5];
    const float* Wv    = (const float*)d_in[6];
    const float* bv    = (const float*)d_in[7];
    const float* Ws1   = (const float*)d_in[8];
    const float* bs1   = (const float*)d_in[9];
    const float* Ws2   = (const float*)d_in[10];
    const float* bs2   = (const float*)d_in[11];
    const float* Wo    = (const float*)d_in[12];
    const float* bo    = (const float*)d_in[13];

    float* outp  = (float*)d_out;
    float* amean = outp + (size_t)M_ * E_;

    char* p = (char*)d_ws;
    auto alloc = [&](size_t bytes) {
        char* r = p; p += (bytes + 255) & ~(size_t)255; return r;
    };
    const size_t SZ_ME  = (size_t)M_ * E_ * 2;
    const size_t SZ_W   = (size_t)E_ * E_ * 2;
    float* swp  = (float*)alloc(128);
    u16* xhi    = (u16*)alloc(SZ_ME);                 // later: ch
    u16* xlo    = (u16*)alloc(SZ_ME);                 // later: cl
    u16* wt_hi  = (u16*)alloc(SZ_W);                  // shared for all 4 weights
    u16* wt_lo  = (u16*)alloc(SZ_W);
    u16* qh     = (u16*)alloc(SZ_ME);
    u16* ql     = (u16*)alloc(SZ_ME);
    u16* kh     = (u16*)alloc(SZ_ME);
    u16* kl     = (u16*)alloc(SZ_ME);
    u16* vth    = (u16*)alloc(SZ_ME);
    u16* vtl    = (u16*)alloc(SZ_ME);
    float* invl = (float*)alloc((size_t)B_ * H_ * S_ * 4);

    const size_t need = (size_t)(p - (char*)d_ws);
    if (ws_size < need) {
        zfill<<<dim3((out_size + 255) / 256), 256, 0, stream>>>(outp, out_size);
        return;
    }

    u16* ch = xhi;
    u16* cl = xlo;

    gate_kernel<<<dim3(B_), 256, 0, stream>>>(syncf, Ws1, bs1, Ws2, bs2, swp);
    split_x<<<dim3(M_ * E_ / 8 / 256), 256, 0, stream>>>(x, xhi, xlo);

    dim3 gt(16, 16);
    dim3 gg(E_ / 128, M_ / 128);
    split_tw<<<gt, 256, 0, stream>>>(Wq, wt_hi, wt_lo);
    gemm_mfma<1><<<gg, 512, 0, stream>>>(xhi, xlo, wt_hi, wt_lo, bq, nullptr, qh, ql);
    split_tw<<<gt, 256, 0, stream>>>(Wk, wt_hi, wt_lo);
    gemm_mfma<1><<<gg, 512, 0, stream>>>(xhi, xlo, wt_hi, wt_lo, bk, nullptr, kh, kl);
    split_tw<<<gt, 256, 0, stream>>>(Wv, wt_hi, wt_lo);
    gemm_mfma<2><<<gg, 512, 0, stream>>>(xhi, xlo, wt_hi, wt_lo, bv, nullptr, vth, vtl);

    // x-split dead from here: ch/cl overwrite xhi/xlo
    attn_pass1<<<dim3(S_ / 256, H_, B_), 512, 0, stream>>>(qh, ql, kh, kl, vth, vtl,
                                                           swp, ch, cl, invl);

    attn_mean<<<dim3(S_ / 128, S_ / 128, B_), 256, 0, stream>>>(qh, ql, kh, kl,
                                                                swp, invl, amean);

    split_tw<<<gt, 256, 0, stream>>>(Wo, wt_hi, wt_lo);
    gemm_mfma<0><<<gg, 512, 0, stream>>>(ch, cl, wt_hi, wt_lo, bo, outp, nullptr, nullptr);
}